// Round 1
// baseline (855.029 us; speedup 1.0000x reference)
//
#include <hip/hip_runtime.h>

typedef __bf16 bf16x8 __attribute__((ext_vector_type(8)));
typedef float f32x4 __attribute__((ext_vector_type(4)));
typedef unsigned int u32x4 __attribute__((ext_vector_type(4)));
typedef unsigned short u16x4 __attribute__((ext_vector_type(4)));

#define S_LEN 2048
#define HDIM  4096
#define KVDIM 1024
#define NHEAD 32
#define NKV   8

__device__ __forceinline__ unsigned short f2b(float x) {
    unsigned int u = __builtin_bit_cast(unsigned int, x);
    u = (u + 0x7FFFu + ((u >> 16) & 1u)) >> 16;
    return (unsigned short)u;
}
__device__ __forceinline__ float b2f(unsigned short b) {
    unsigned int u = ((unsigned int)b) << 16;
    return __builtin_bit_cast(float, u);
}

// ---------------- f32 -> bf16 conversion ----------------
__global__ void cvt_kernel(const float* __restrict__ in, unsigned short* __restrict__ out, int n4) {
    int i = blockIdx.x * 256 + threadIdx.x;
    if (i >= n4) return;
    f32x4 v = ((const f32x4*)in)[i];
    u16x4 o;
    o.x = f2b(v.x); o.y = f2b(v.y); o.z = f2b(v.z); o.w = f2b(v.w);
    ((u16x4*)out)[i] = o;
}

// ---------------- NT GEMM: C[M,N] = A[M,K] @ B[N,K]^T (bf16 in, fp32 acc) ----------
// MODE 0: C bf16 row-major [M,N]; MODE 1: C bf16 transposed [N,M]; MODE 2: C f32 [M,N]
template <int MODE>
__global__ __launch_bounds__(256) void gemm_nt(const unsigned short* __restrict__ A,
                                               const unsigned short* __restrict__ B,
                                               void* __restrict__ Cv, int M, int N, int K) {
    __shared__ unsigned short As[128][72];  // 64 k + 8 pad; rows 16B aligned (144 B)
    __shared__ unsigned short Bs[128][72];
    const int tid = threadIdx.x;
    const int w = tid >> 6, lane = tid & 63, quad = lane >> 4, l15 = lane & 15;
    const int wy = w >> 1, wx = w & 1;
    const int m0 = blockIdx.y * 128, n0 = blockIdx.x * 128;
    const int srow = tid >> 3;   // 0..31
    const int sseg = tid & 7;    // 0..7 (16B segments of a 128B row)

    f32x4 acc[4][4] = {};

    for (int k0 = 0; k0 < K; k0 += 64) {
#pragma unroll
        for (int p = 0; p < 4; ++p) {
            int r = srow + p * 32;
            *(u32x4*)&As[r][sseg * 8] = *(const u32x4*)&A[(size_t)(m0 + r) * K + k0 + sseg * 8];
            *(u32x4*)&Bs[r][sseg * 8] = *(const u32x4*)&B[(size_t)(n0 + r) * K + k0 + sseg * 8];
        }
        __syncthreads();
#pragma unroll
        for (int t = 0; t < 2; ++t) {
            bf16x8 af[4], bfr[4];
#pragma unroll
            for (int mb = 0; mb < 4; ++mb)
                af[mb] = *(const bf16x8*)&As[wy * 64 + mb * 16 + l15][t * 32 + quad * 8];
#pragma unroll
            for (int nb = 0; nb < 4; ++nb)
                bfr[nb] = *(const bf16x8*)&Bs[wx * 64 + nb * 16 + l15][t * 32 + quad * 8];
#pragma unroll
            for (int mb = 0; mb < 4; ++mb)
#pragma unroll
                for (int nb = 0; nb < 4; ++nb)
                    acc[mb][nb] = __builtin_amdgcn_mfma_f32_16x16x32_bf16(af[mb], bfr[nb], acc[mb][nb], 0, 0, 0);
        }
        __syncthreads();
    }
#pragma unroll
    for (int mb = 0; mb < 4; ++mb)
#pragma unroll
        for (int nb = 0; nb < 4; ++nb)
#pragma unroll
            for (int r = 0; r < 4; ++r) {
                int row = m0 + wy * 64 + mb * 16 + quad * 4 + r;
                int col = n0 + wx * 64 + nb * 16 + l15;
                float v = acc[mb][nb][r];
                if (MODE == 0)
                    ((unsigned short*)Cv)[(size_t)row * N + col] = f2b(v);
                else if (MODE == 1)
                    ((unsigned short*)Cv)[(size_t)col * M + row] = f2b(v);
                else
                    ((float*)Cv)[(size_t)row * N + col] = v;
            }
}

// ---------------- RoPE (in-place, bf16 Q [S,4096] and K [S,1024]) ----------------
__global__ void rope_kernel(unsigned short* __restrict__ Q, unsigned short* __restrict__ Kc,
                            const int* __restrict__ pos_ids) {
    int tid = blockIdx.x * 256 + threadIdx.x;  // S * 40 heads * 64 pairs
    int j = tid & 63;
    int head = (tid >> 6) % (NHEAD + NKV);
    int s = tid / (64 * (NHEAD + NKV));
    float pos = (float)pos_ids[s];
    // inv_freq = 10000^(-2j/128) = 2^(-j * log2(10000)/64)
    float inv = exp2f(-(float)j * 0.20762050593046f);
    float ang = pos * inv;
    float sn, cs;
    __sincosf(ang, &sn, &cs);
    unsigned short* p;
    if (head < NHEAD)
        p = Q + (size_t)s * HDIM + head * 128;
    else
        p = Kc + (size_t)s * KVDIM + (head - NHEAD) * 128;
    float x1 = b2f(p[j]), x2 = b2f(p[j + 64]);
    p[j] = f2b(x1 * cs - x2 * sn);
    p[j + 64] = f2b(x2 * cs + x1 * sn);
}

// ---------------- causal GQA flash attention ----------------
// Q [S,4096] bf16 (post-RoPE), Kb [S,1024] bf16 (post-RoPE), Vt [1024,S] bf16 (V transposed)
// O [S,4096] bf16.  grid = (S/64, NHEAD), block = 256 (4 waves x 16 q-rows)
__global__ __launch_bounds__(256) void attn_fwd(const unsigned short* __restrict__ Q,
                                                const unsigned short* __restrict__ Kb,
                                                const unsigned short* __restrict__ Vt,
                                                unsigned short* __restrict__ O) {
    __shared__ unsigned short Ks[64][136];   // [kpos][d]   rows 272 B (16B aligned)
    __shared__ unsigned short Vts[128][72];  // [d][kpos]   rows 144 B
    __shared__ unsigned short Ps[4][16][72]; // per-wave P  rows 144 B

    const int qblk = blockIdx.x, h = blockIdx.y, kvh = h >> 2;
    const int tid = threadIdx.x, w = tid >> 6, lane = tid & 63;
    const int quad = lane >> 4, l15 = lane & 15;
    const int qg = qblk * 64 + w * 16 + l15;  // q-row this lane's A-frags come from

    bf16x8 aq[4];
#pragma unroll
    for (int t = 0; t < 4; ++t)
        aq[t] = *(const bf16x8*)&Q[(size_t)qg * HDIM + h * 128 + t * 32 + quad * 8];

    f32x4 o[8] = {};
    float m_r[4], l_r[4];
#pragma unroll
    for (int r = 0; r < 4; ++r) { m_r[r] = -3.0e38f; l_r[r] = 0.f; }
    const float cexp = 0.08838834764831845f * 1.4426950408889634f;  // 1/sqrt(128)*log2(e)
    const int qrow_base = qblk * 64 + w * 16 + quad * 4;

    const int kr0 = tid >> 4, ksg = tid & 15;  // K staging: 16 rows/pass x 16 segs
    const int vr0 = tid >> 3, vsg = tid & 7;   // V staging: 32 rows/pass x 8 segs

    for (int kt = 0; kt <= qblk; ++kt) {
        const int k0 = kt * 64;
#pragma unroll
        for (int p = 0; p < 4; ++p) {
            int r = kr0 + p * 16;
            *(u32x4*)&Ks[r][ksg * 8] = *(const u32x4*)&Kb[(size_t)(k0 + r) * KVDIM + kvh * 128 + ksg * 8];
        }
#pragma unroll
        for (int p = 0; p < 4; ++p) {
            int r = vr0 + p * 32;
            *(u32x4*)&Vts[r][vsg * 8] = *(const u32x4*)&Vt[(size_t)(kvh * 128 + r) * S_LEN + k0 + vsg * 8];
        }
        __syncthreads();

        // S = Q K^T  (16 q-rows x 64 k-cols per wave)
        f32x4 sc[4] = {};
#pragma unroll
        for (int t = 0; t < 4; ++t)
#pragma unroll
            for (int nb = 0; nb < 4; ++nb) {
                bf16x8 bk = *(const bf16x8*)&Ks[nb * 16 + l15][t * 32 + quad * 8];
                sc[nb] = __builtin_amdgcn_mfma_f32_16x16x32_bf16(aq[t], bk, sc[nb], 0, 0, 0);
            }

        // online softmax, one row per (quad, r)
#pragma unroll
        for (int r = 0; r < 4; ++r) {
            const int q = qrow_base + r;
            float v[4];
#pragma unroll
            for (int nb = 0; nb < 4; ++nb) {
                int kcol = k0 + nb * 16 + l15;
                v[nb] = (kcol <= q) ? sc[nb][r] * cexp : -3.0e38f;
            }
            float mx = fmaxf(fmaxf(v[0], v[1]), fmaxf(v[2], v[3]));
#pragma unroll
            for (int d = 1; d < 16; d <<= 1) mx = fmaxf(mx, __shfl_xor(mx, d, 64));
            float mnew = fmaxf(m_r[r], mx);
            float alpha = exp2f(m_r[r] - mnew);
            float sum = 0.f;
#pragma unroll
            for (int nb = 0; nb < 4; ++nb) {
                float pp = exp2f(v[nb] - mnew);
                sum += pp;
                Ps[w][quad * 4 + r][nb * 16 + l15] = f2b(pp);
            }
#pragma unroll
            for (int d = 1; d < 16; d <<= 1) sum += __shfl_xor(sum, d, 64);
            l_r[r] = l_r[r] * alpha + sum;
            m_r[r] = mnew;
#pragma unroll
            for (int db = 0; db < 8; ++db) o[db][r] *= alpha;
        }

        // O += P V : P C-layout -> A-layout via LDS round trip
        bf16x8 pa[2];
#pragma unroll
        for (int t = 0; t < 2; ++t)
            pa[t] = *(const bf16x8*)&Ps[w][l15][t * 32 + quad * 8];
#pragma unroll
        for (int db = 0; db < 8; ++db)
#pragma unroll
            for (int t = 0; t < 2; ++t) {
                bf16x8 vb = *(const bf16x8*)&Vts[db * 16 + l15][t * 32 + quad * 8];
                o[db] = __builtin_amdgcn_mfma_f32_16x16x32_bf16(pa[t], vb, o[db], 0, 0, 0);
            }
        __syncthreads();
    }

#pragma unroll
    for (int db = 0; db < 8; ++db)
#pragma unroll
        for (int r = 0; r < 4; ++r) {
            int row = qrow_base + r;
            int col = h * 128 + db * 16 + l15;
            O[(size_t)row * HDIM + col] = f2b(o[db][r] / l_r[r]);
        }
}

extern "C" void kernel_launch(void* const* d_in, const int* in_sizes, int n_in,
                              void* d_out, int out_size, void* d_ws, size_t ws_size,
                              hipStream_t stream) {
    const float* hid = (const float*)d_in[0];
    const int* pos   = (const int*)d_in[1];
    const float* Wq  = (const float*)d_in[2];
    const float* Wk  = (const float*)d_in[3];
    const float* Wv  = (const float*)d_in[4];
    const float* Wo  = (const float*)d_in[5];
    float* out = (float*)d_out;

    char* ws = (char*)d_ws;
    // bf16 buffers (sizes in bytes):
    unsigned short* hb   = (unsigned short*)(ws);               // 16 MiB  [S,H]
    unsigned short* Wqb  = (unsigned short*)(ws + 16777216);    // 32 MiB
    unsigned short* Wkb  = (unsigned short*)(ws + 50331648);    // 8 MiB
    unsigned short* Wvb  = (unsigned short*)(ws + 58720256);    // 8 MiB
    unsigned short* Wob  = (unsigned short*)(ws + 67108864);    // 32 MiB
    unsigned short* Qw   = (unsigned short*)(ws + 100663296);   // 16 MiB
    unsigned short* Kw   = (unsigned short*)(ws + 117440512);   // 4 MiB
    unsigned short* Vtw  = Wqb;  // reuse Wq region (Wq consumed before V GEMM writes)
    unsigned short* attw = hb;   // reuse hidden region (consumed before attention writes)

    // 1. f32 -> bf16
    cvt_kernel<<<(S_LEN * HDIM / 4 + 255) / 256, 256, 0, stream>>>(hid, hb, S_LEN * HDIM / 4);
    cvt_kernel<<<(HDIM * HDIM / 4 + 255) / 256, 256, 0, stream>>>(Wq, Wqb, HDIM * HDIM / 4);
    cvt_kernel<<<(KVDIM * HDIM / 4 + 255) / 256, 256, 0, stream>>>(Wk, Wkb, KVDIM * HDIM / 4);
    cvt_kernel<<<(KVDIM * HDIM / 4 + 255) / 256, 256, 0, stream>>>(Wv, Wvb, KVDIM * HDIM / 4);
    cvt_kernel<<<(HDIM * HDIM / 4 + 255) / 256, 256, 0, stream>>>(Wo, Wob, HDIM * HDIM / 4);

    // 2. projections
    gemm_nt<0><<<dim3(HDIM / 128, S_LEN / 128), 256, 0, stream>>>(hb, Wqb, Qw, S_LEN, HDIM, HDIM);
    gemm_nt<0><<<dim3(KVDIM / 128, S_LEN / 128), 256, 0, stream>>>(hb, Wkb, Kw, S_LEN, KVDIM, HDIM);
    gemm_nt<1><<<dim3(KVDIM / 128, S_LEN / 128), 256, 0, stream>>>(hb, Wvb, Vtw, S_LEN, KVDIM, HDIM);

    // 3. RoPE on Q,K
    rope_kernel<<<S_LEN * (NHEAD + NKV) * 64 / 256, 256, 0, stream>>>(Qw, Kw, pos);

    // 4. causal GQA attention
    attn_fwd<<<dim3(S_LEN / 64, NHEAD), 256, 0, stream>>>(Qw, Kw, Vtw, attw);

    // 5. output projection -> f32
    gemm_nt<2><<<dim3(HDIM / 128, S_LEN / 128), 256, 0, stream>>>(attw, Wob, out, S_LEN, HDIM, HDIM);
}

// Round 2
// 560.991 us; speedup vs baseline: 1.5241x; 1.5241x over previous
//
#include <hip/hip_runtime.h>

typedef __bf16 bf16x8 __attribute__((ext_vector_type(8)));
typedef float f32x4 __attribute__((ext_vector_type(4)));
typedef unsigned int u32x4 __attribute__((ext_vector_type(4)));
typedef unsigned short u16x4 __attribute__((ext_vector_type(4)));
typedef unsigned short ushort_t;

#define S_LEN 2048
#define HDIM  4096
#define KVDIM 1024
#define NHEAD 32
#define NKV   8

__device__ __forceinline__ unsigned short f2b(float x) {
    unsigned int u = __builtin_bit_cast(unsigned int, x);
    u = (u + 0x7FFFu + ((u >> 16) & 1u)) >> 16;
    return (unsigned short)u;
}
__device__ __forceinline__ float b2f(unsigned short b) {
    unsigned int u = ((unsigned int)b) << 16;
    return __builtin_bit_cast(float, u);
}

// async global->LDS 16B copy (gfx950): LDS dest must be wave-uniform base + lane*16
__device__ __forceinline__ void gl_lds16(const void* g, void* s) {
    __builtin_amdgcn_global_load_lds(
        (const __attribute__((address_space(1))) unsigned int*)g,
        (__attribute__((address_space(3))) unsigned int*)s, 16, 0, 0);
}

// ---------------- f32 -> bf16 conversion ----------------
__global__ void cvt_kernel(const float* __restrict__ in, unsigned short* __restrict__ out, int n4) {
    int i = blockIdx.x * 256 + threadIdx.x;
    if (i >= n4) return;
    f32x4 v = ((const f32x4*)in)[i];
    u16x4 o;
    o.x = f2b(v.x); o.y = f2b(v.y); o.z = f2b(v.z); o.w = f2b(v.w);
    ((u16x4*)out)[i] = o;
}

// ---------------- NT GEMM body: C[M,N] = A[M,K] @ B[N,K]^T ----------------
// m97 structure: global_load_lds width-16 staging into UNPADDED LDS tiles with
// XOR-chunk swizzle folded into the GLOBAL address (LDS dest stays base+lane*16).
// MODE 0: C bf16 [M,N]; MODE 1: C bf16 transposed [N,M]; MODE 2: C f32 [M,N]
template <int MODE>
__device__ __forceinline__ void gemm_body(const unsigned short* __restrict__ A,
                                          const unsigned short* __restrict__ B,
                                          void* __restrict__ Cv,
                                          int M, int N, int K, int m0, int n0,
                                          unsigned short (*As)[64], unsigned short (*Bs)[64]) {
    const int tid = threadIdx.x;
    const int w = tid >> 6, lane = tid & 63, quad = lane >> 4, l15 = lane & 15;
    const int wy = w >> 1, wx = w & 1;
    // staging: each wave covers 8 rows/pass, 4 passes -> 32 rows; 4 waves -> 128 rows
    const int srowb = w * 32 + (lane >> 3);          // + p*8
    const int gchunk = (lane & 7) ^ (lane >> 3);     // XOR swizzle (r&7 == lane>>3)
    const int lcol = (lane & 7) * 8;                 // LDS slot col (elements)

    f32x4 acc[4][4] = {};

    for (int k0 = 0; k0 < K; k0 += 64) {
#pragma unroll
        for (int p = 0; p < 4; ++p) {
            int r = srowb + p * 8;
            gl_lds16(&A[(size_t)(m0 + r) * K + k0 + gchunk * 8], &As[r][lcol]);
            gl_lds16(&B[(size_t)(n0 + r) * K + k0 + gchunk * 8], &Bs[r][lcol]);
        }
        __syncthreads();
#pragma unroll
        for (int t = 0; t < 2; ++t) {
            bf16x8 af[4], bfr[4];
#pragma unroll
            for (int mb = 0; mb < 4; ++mb)
                af[mb] = *(const bf16x8*)&As[wy * 64 + mb * 16 + l15][(((t * 4 + quad) ^ (l15 & 7)) * 8)];
#pragma unroll
            for (int nb = 0; nb < 4; ++nb)
                bfr[nb] = *(const bf16x8*)&Bs[wx * 64 + nb * 16 + l15][(((t * 4 + quad) ^ (l15 & 7)) * 8)];
#pragma unroll
            for (int mb = 0; mb < 4; ++mb)
#pragma unroll
                for (int nb = 0; nb < 4; ++nb)
                    acc[mb][nb] = __builtin_amdgcn_mfma_f32_16x16x32_bf16(af[mb], bfr[nb], acc[mb][nb], 0, 0, 0);
        }
        __syncthreads();
    }
#pragma unroll
    for (int mb = 0; mb < 4; ++mb)
#pragma unroll
        for (int nb = 0; nb < 4; ++nb)
#pragma unroll
            for (int r = 0; r < 4; ++r) {
                int row = m0 + wy * 64 + mb * 16 + quad * 4 + r;
                int col = n0 + wx * 64 + nb * 16 + l15;
                float v = acc[mb][nb][r];
                if (MODE == 0)
                    ((unsigned short*)Cv)[(size_t)row * N + col] = f2b(v);
                else if (MODE == 1)
                    ((unsigned short*)Cv)[(size_t)col * M + row] = f2b(v);
                else
                    ((float*)Cv)[(size_t)row * N + col] = v;
            }
}

template <int MODE>
__global__ __launch_bounds__(256) void gemm_nt(const unsigned short* __restrict__ A,
                                               const unsigned short* __restrict__ B,
                                               void* __restrict__ Cv, int M, int N, int K) {
    __shared__ unsigned short As[128][64];
    __shared__ unsigned short Bs[128][64];
    gemm_body<MODE>(A, B, Cv, M, N, K, blockIdx.y * 128, blockIdx.x * 128, As, Bs);
}

// fused K-proj (MODE0 -> Kw) + V-proj (MODE1 -> Vt) : grid (16,16), full-CU launch
__global__ __launch_bounds__(256) void gemm_kv(const unsigned short* __restrict__ A,
                                               const unsigned short* __restrict__ Bk,
                                               const unsigned short* __restrict__ Bv,
                                               void* __restrict__ Ck, void* __restrict__ Cvt,
                                               int M, int K) {
    __shared__ unsigned short As[128][64];
    __shared__ unsigned short Bs[128][64];
    if (blockIdx.x < 8)
        gemm_body<0>(A, Bk, Ck, M, KVDIM, K, blockIdx.y * 128, blockIdx.x * 128, As, Bs);
    else
        gemm_body<1>(A, Bv, Cvt, M, KVDIM, K, blockIdx.y * 128, (blockIdx.x - 8) * 128, As, Bs);
}

// ---------------- RoPE (in-place, bf16 Q [S,4096] and K [S,1024]) ----------------
__global__ void rope_kernel(unsigned short* __restrict__ Q, unsigned short* __restrict__ Kc,
                            const int* __restrict__ pos_ids) {
    int tid = blockIdx.x * 256 + threadIdx.x;  // S * 40 heads * 64 pairs
    int j = tid & 63;
    int head = (tid >> 6) % (NHEAD + NKV);
    int s = tid / (64 * (NHEAD + NKV));
    float pos = (float)pos_ids[s];
    float inv = exp2f(-(float)j * 0.20762050593046f);  // 10000^(-j/64)
    float ang = pos * inv;
    float sn, cs;
    __sincosf(ang, &sn, &cs);
    unsigned short* p;
    if (head < NHEAD)
        p = Q + (size_t)s * HDIM + head * 128;
    else
        p = Kc + (size_t)s * KVDIM + (head - NHEAD) * 128;
    float x1 = b2f(p[j]), x2 = b2f(p[j + 64]);
    p[j] = f2b(x1 * cs - x2 * sn);
    p[j + 64] = f2b(x2 * cs + x1 * sn);
}

// ---------------- causal GQA flash attention (S^T orientation) ----------------
// Q [S,4096] (post-RoPE), Kb [S,1024] (post-RoPE), Vt [1024,S] (V transposed)
// grid = (NHEAD, S/64), qblk = (S/64-1) - blockIdx.y  => heavy blocks dispatch FIRST
// block = 256 = 4 waves; wave w owns q rows [qblk*64 + w*16, +16)
// S^T = K Q^T so the softmax k-reduction is register-local + 2 shfl (not 16-lane).
__global__ __launch_bounds__(256) void attn_fwd(const unsigned short* __restrict__ Q,
                                                const unsigned short* __restrict__ Kb,
                                                const unsigned short* __restrict__ Vt,
                                                unsigned short* __restrict__ O) {
    __shared__ unsigned short Ks[64][136];   // [kpos][d]
    __shared__ unsigned short Vts[128][72];  // [d][kpos]
    __shared__ unsigned short Ps[4][16][80]; // per-wave P [q_local][kpos], 160B rows

    const int qblk = (gridDim.y - 1) - blockIdx.y;
    const int h = blockIdx.x, kvh = h >> 2;
    const int tid = threadIdx.x, w = tid >> 6, lane = tid & 63;
    const int quad = lane >> 4, l15 = lane & 15;
    const int qg = qblk * 64 + w * 16 + l15;  // this lane's q row (for B-frag & softmax state)

    bf16x8 aq[4];
#pragma unroll
    for (int t = 0; t < 4; ++t)
        aq[t] = *(const bf16x8*)&Q[(size_t)qg * HDIM + h * 128 + t * 32 + quad * 8];

    f32x4 o[8] = {};
    float m_s = -3.0e38f, l_s = 0.f;  // softmax state for q = qg (replicated over quads)
    const float cexp = 0.08838834764831845f * 1.4426950408889634f;  // 1/sqrt(128)*log2(e)

    const int kr0 = tid >> 4, ksg = tid & 15;  // K staging: 16 rows/pass x 16 segs
    const int vr0 = tid >> 3, vsg = tid & 7;   // V staging: 32 rows/pass x 8 segs

    // prefetch tile 0
    u32x4 kpre[4], vpre[4];
#pragma unroll
    for (int p = 0; p < 4; ++p) {
        kpre[p] = *(const u32x4*)&Kb[(size_t)(kr0 + p * 16) * KVDIM + kvh * 128 + ksg * 8];
        vpre[p] = *(const u32x4*)&Vt[(size_t)(kvh * 128 + vr0 + p * 32) * S_LEN + vsg * 8];
    }

    for (int kt = 0; kt <= qblk; ++kt) {
#pragma unroll
        for (int p = 0; p < 4; ++p) {
            *(u32x4*)&Ks[kr0 + p * 16][ksg * 8] = kpre[p];
            *(u32x4*)&Vts[vr0 + p * 32][vsg * 8] = vpre[p];
        }
        __syncthreads();
        if (kt < qblk) {  // prefetch next tile; loads fly while we compute below
            const int k0n = kt * 64 + 64;
#pragma unroll
            for (int p = 0; p < 4; ++p) {
                kpre[p] = *(const u32x4*)&Kb[(size_t)(k0n + kr0 + p * 16) * KVDIM + kvh * 128 + ksg * 8];
                vpre[p] = *(const u32x4*)&Vt[(size_t)(kvh * 128 + vr0 + p * 32) * S_LEN + k0n + vsg * 8];
            }
        }

        // S^T = K Q^T : rows = k (64), cols = q (16/wave)
        f32x4 sc[4] = {};
#pragma unroll
        for (int t = 0; t < 4; ++t)
#pragma unroll
            for (int mb = 0; mb < 4; ++mb) {
                bf16x8 ak = *(const bf16x8*)&Ks[mb * 16 + l15][t * 32 + quad * 8];
                sc[mb] = __builtin_amdgcn_mfma_f32_16x16x32_bf16(ak, aq[t], sc[mb], 0, 0, 0);
            }

        // softmax for q = qg; this lane holds k = mb*16 + quad*4 + r
        float vv[16];
        if (kt == qblk) {  // diagonal tile: causal mask (uniform branch)
#pragma unroll
            for (int mb = 0; mb < 4; ++mb)
#pragma unroll
                for (int r = 0; r < 4; ++r) {
                    int kl = mb * 16 + quad * 4 + r;
                    vv[mb * 4 + r] = (kl <= w * 16 + l15) ? sc[mb][r] * cexp : -3.0e38f;
                }
        } else {
#pragma unroll
            for (int mb = 0; mb < 4; ++mb)
#pragma unroll
                for (int r = 0; r < 4; ++r)
                    vv[mb * 4 + r] = sc[mb][r] * cexp;
        }
        float mx = vv[0];
#pragma unroll
        for (int i = 1; i < 16; ++i) mx = fmaxf(mx, vv[i]);
        mx = fmaxf(mx, __shfl_xor(mx, 16, 64));
        mx = fmaxf(mx, __shfl_xor(mx, 32, 64));
        float mnew = fmaxf(m_s, mx);
        float alpha = exp2f(m_s - mnew);
        m_s = mnew;
        float sum = 0.f;
        unsigned short pb[16];
#pragma unroll
        for (int i = 0; i < 16; ++i) {
            float pp = exp2f(vv[i] - mnew);
            sum += pp;
            pb[i] = f2b(pp);
        }
        sum += __shfl_xor(sum, 16, 64);
        sum += __shfl_xor(sum, 32, 64);
        l_s = l_s * alpha + sum;
        // store P to A-operand home: Ps[w][q_local=l15][k], packed 8B
#pragma unroll
        for (int mb = 0; mb < 4; ++mb) {
            u16x4 pk = {pb[mb * 4 + 0], pb[mb * 4 + 1], pb[mb * 4 + 2], pb[mb * 4 + 3]};
            *(u16x4*)&Ps[w][l15][mb * 16 + quad * 4] = pk;
        }
        // rescale o: row q_local = quad*4 + r needs alpha from lane l15'=quad*4+r (same quad)
        float a4[4];
#pragma unroll
        for (int r = 0; r < 4; ++r) a4[r] = __shfl(alpha, quad * 20 + r, 64);
#pragma unroll
        for (int db = 0; db < 8; ++db)
#pragma unroll
            for (int r = 0; r < 4; ++r) o[db][r] *= a4[r];

        // O += P V
        bf16x8 pa[2];
#pragma unroll
        for (int t = 0; t < 2; ++t)
            pa[t] = *(const bf16x8*)&Ps[w][l15][t * 32 + quad * 8];
#pragma unroll
        for (int db = 0; db < 8; ++db)
#pragma unroll
            for (int t = 0; t < 2; ++t) {
                bf16x8 vb = *(const bf16x8*)&Vts[db * 16 + l15][t * 32 + quad * 8];
                o[db] = __builtin_amdgcn_mfma_f32_16x16x32_bf16(pa[t], vb, o[db], 0, 0, 0);
            }
        __syncthreads();
    }

    float linv[4];
#pragma unroll
    for (int r = 0; r < 4; ++r) linv[r] = 1.0f / __shfl(l_s, quad * 20 + r, 64);
    const int qrow_base = qblk * 64 + w * 16 + quad * 4;
#pragma unroll
    for (int db = 0; db < 8; ++db)
#pragma unroll
        for (int r = 0; r < 4; ++r) {
            int row = qrow_base + r;
            int col = h * 128 + db * 16 + l15;
            O[(size_t)row * HDIM + col] = f2b(o[db][r] * linv[r]);
        }
}

extern "C" void kernel_launch(void* const* d_in, const int* in_sizes, int n_in,
                              void* d_out, int out_size, void* d_ws, size_t ws_size,
                              hipStream_t stream) {
    const float* hid = (const float*)d_in[0];
    const int* pos   = (const int*)d_in[1];
    const float* Wq  = (const float*)d_in[2];
    const float* Wk  = (const float*)d_in[3];
    const float* Wv  = (const float*)d_in[4];
    const float* Wo  = (const float*)d_in[5];
    float* out = (float*)d_out;

    char* ws = (char*)d_ws;
    unsigned short* hb   = (unsigned short*)(ws);               // 16 MiB  [S,H]
    unsigned short* Wqb  = (unsigned short*)(ws + 16777216);    // 32 MiB
    unsigned short* Wkb  = (unsigned short*)(ws + 50331648);    // 8 MiB
    unsigned short* Wvb  = (unsigned short*)(ws + 58720256);    // 8 MiB
    unsigned short* Wob  = (unsigned short*)(ws + 67108864);    // 32 MiB
    unsigned short* Qw   = (unsigned short*)(ws + 100663296);   // 16 MiB
    unsigned short* Kw   = (unsigned short*)(ws + 117440512);   // 4 MiB
    unsigned short* Vtw  = Wqb;  // reuse Wq region (consumed before V GEMM writes)
    unsigned short* attw = hb;   // reuse hidden region (consumed before attention writes)

    // 1. f32 -> bf16
    cvt_kernel<<<(S_LEN * HDIM / 4 + 255) / 256, 256, 0, stream>>>(hid, hb, S_LEN * HDIM / 4);
    cvt_kernel<<<(HDIM * HDIM / 4 + 255) / 256, 256, 0, stream>>>(Wq, Wqb, HDIM * HDIM / 4);
    cvt_kernel<<<(KVDIM * HDIM / 4 + 255) / 256, 256, 0, stream>>>(Wk, Wkb, KVDIM * HDIM / 4);
    cvt_kernel<<<(KVDIM * HDIM / 4 + 255) / 256, 256, 0, stream>>>(Wv, Wvb, KVDIM * HDIM / 4);
    cvt_kernel<<<(HDIM * HDIM / 4 + 255) / 256, 256, 0, stream>>>(Wo, Wob, HDIM * HDIM / 4);

    // 2. projections: Q, then fused K+V
    gemm_nt<0><<<dim3(HDIM / 128, S_LEN / 128), 256, 0, stream>>>(hb, Wqb, Qw, S_LEN, HDIM, HDIM);
    gemm_kv<<<dim3(16, S_LEN / 128), 256, 0, stream>>>(hb, Wkb, Wvb, Kw, Vtw, S_LEN, HDIM);

    // 3. RoPE on Q,K
    rope_kernel<<<S_LEN * (NHEAD + NKV) * 64 / 256, 256, 0, stream>>>(Qw, Kw, pos);

    // 4. causal GQA attention (heavy-first dispatch)
    attn_fwd<<<dim3(NHEAD, S_LEN / 64), 256, 0, stream>>>(Qw, Kw, Vtw, attw);

    // 5. output projection -> f32
    gemm_nt<2><<<dim3(HDIM / 128, S_LEN / 128), 256, 0, stream>>>(attw, Wob, out, S_LEN, HDIM, HDIM);
}